// Round 10
// baseline (264.777 us; speedup 1.0000x reference)
//
#include <hip/hip_runtime.h>
#include <hip/hip_bf16.h>

#define NN 100000
#define NE 640000
#define D 128

#define SCAN_CHUNK 1024
#define NBLK ((NN + SCAN_CHUNK - 1) / SCAN_CHUNK)   // 98

// ---- workspace layout (bytes) ----
#define OFF_COUNTS  0u                         // NN*4
#define OFF_OFFSETS 400000u                    // (NN+1)*4, padded
#define OFF_CURSOR  800016u                    // NN*4
#define OFF_BSUM    1200016u                   // 512 B
#define OFF_BSUMEX  1200528u                   // 512 B
#define OFF_PE      1201040u                   // NE*8  (int2 packed src,w)
#define WS_T2       6321040u                   // tier-2 end
#define OFF_XB      6321040u                   // NN*64*4 (packed bf16x2 rows)
#define WS_FULL     31921040u                  // tier-1 end

typedef __attribute__((ext_vector_type(8))) short bf16x8;
typedef __attribute__((ext_vector_type(4))) float f32x4;

__device__ __forceinline__ float bflo(unsigned u) { return __uint_as_float(u << 16); }
__device__ __forceinline__ float bfhi(unsigned u) { return __uint_as_float(u & 0xffff0000u); }
__device__ __forceinline__ unsigned bfpk(float x, float y) {
    __hip_bfloat16 bx = __float2bfloat16(x), by = __float2bfloat16(y);
    return (unsigned)(*(unsigned short*)&bx) | ((unsigned)(*(unsigned short*)&by) << 16);
}

// ---------------------------------------------------------------------------
// histogram of targets
// ---------------------------------------------------------------------------
__global__ __launch_bounds__(256) void k_hist(const int* __restrict__ tgt,
                                              int* __restrict__ counts) {
    int e = blockIdx.x * 256 + threadIdx.x;
    if (e < NE) atomicAdd(&counts[tgt[e]], 1);
}

// ---------------------------------------------------------------------------
// multi-block scan (round-5 verified): partial sums -> mid scan -> final
// ---------------------------------------------------------------------------
__global__ __launch_bounds__(256) void k_scan_part(const int* __restrict__ counts,
                                                   int* __restrict__ bsum) {
    __shared__ int sd[256];
    int b = blockIdx.x, t = threadIdx.x;
    int base = b * SCAN_CHUNK + t * 4;
    int s = 0;
    #pragma unroll
    for (int k = 0; k < 4; ++k) { int i = base + k; s += (i < NN) ? counts[i] : 0; }
    sd[t] = s; __syncthreads();
    for (int off = 128; off > 0; off >>= 1) {
        if (t < off) sd[t] += sd[t + off];
        __syncthreads();
    }
    if (t == 0) bsum[b] = sd[0];
}

__global__ __launch_bounds__(128) void k_scan_mid(const int* __restrict__ bsum,
                                                  int* __restrict__ bsumex,
                                                  int* __restrict__ offsets) {
    __shared__ int sd[128];
    int t = threadIdx.x;
    int v = (t < NBLK) ? bsum[t] : 0;
    sd[t] = v; __syncthreads();
    for (int off = 1; off < 128; off <<= 1) {
        int tmp = (t >= off) ? sd[t - off] : 0;
        __syncthreads();
        sd[t] += tmp;
        __syncthreads();
    }
    if (t < NBLK) bsumex[t] = sd[t] - v;
    if (t == 0) offsets[NN] = NE;
}

__global__ __launch_bounds__(256) void k_scan_final(const int* __restrict__ counts,
                                                    const int* __restrict__ bsumex,
                                                    int* __restrict__ offsets,
                                                    int* __restrict__ cursor) {
    __shared__ int sd[256];
    int b = blockIdx.x, t = threadIdx.x;
    int base = b * SCAN_CHUNK + t * 4;
    int c[4]; int s = 0;
    #pragma unroll
    for (int k = 0; k < 4; ++k) { int i = base + k; c[k] = (i < NN) ? counts[i] : 0; s += c[k]; }
    sd[t] = s; __syncthreads();
    for (int off = 1; off < 256; off <<= 1) {
        int tmp = (t >= off) ? sd[t - off] : 0;
        __syncthreads();
        sd[t] += tmp;
        __syncthreads();
    }
    int run = sd[t] - s + bsumex[b];
    #pragma unroll
    for (int k = 0; k < 4; ++k) {
        int i = base + k;
        if (i < NN) { offsets[i] = run; cursor[i] = run; }
        run += c[k];
    }
}

// ---------------------------------------------------------------------------
// fused: bucket edges (blocks 0..FILL_BLKS) + x->bf16 conv (remaining blocks)
// ---------------------------------------------------------------------------
#define FILL_BLKS ((NE + 255) / 256)           // 2500
#define CONV_BLKS ((NN * 64 + 255) / 256)      // 25000

__global__ __launch_bounds__(256) void k_fill_conv(const int* __restrict__ src,
                                                   const int* __restrict__ tgt,
                                                   const float* __restrict__ ew,
                                                   int* __restrict__ cursor,
                                                   int2* __restrict__ pe,
                                                   const float* __restrict__ x,
                                                   unsigned* __restrict__ xb) {
    int b = blockIdx.x;
    if (b < FILL_BLKS) {
        int e = b * 256 + threadIdx.x;
        if (e < NE) {
            int t = tgt[e];
            int p = atomicAdd(&cursor[t], 1);
            pe[p] = make_int2(src[e], __float_as_int(ew[e]));
        }
    } else {
        int i = (b - FILL_BLKS) * 256 + threadIdx.x;
        if (i < NN * 64) {
            float2 v = ((const float2*)x)[i];
            xb[i] = bfpk(v.x, v.y);
        }
    }
}

// tier-2 variant: fill only
__global__ __launch_bounds__(256) void k_fill(const int* __restrict__ src,
                                              const int* __restrict__ tgt,
                                              const float* __restrict__ ew,
                                              int* __restrict__ cursor,
                                              int2* __restrict__ pe) {
    int e = blockIdx.x * 256 + threadIdx.x;
    if (e < NE) {
        int t = tgt[e];
        int p = atomicAdd(&cursor[t], 1);
        pe[p] = make_int2(src[e], __float_as_int(ew[e]));
    }
}

// ---------------------------------------------------------------------------
// FUSED gather + MFMA projection (tier-1).
// 512 thr = 8 waves, 64 nodes/block. Wave w gathers nodes w*8..w*8+7 into
// LDS As (bf16), barrier, then wave-pairs project 16 rows each via
// mfma_f32_16x16x32_bf16 (wave w: col-tiles (w&1)*4..+3), write fp32 out.
// LDS 52 KB -> 3 blocks/CU (24 waves/CU). Numerics identical to round-9.
// ---------------------------------------------------------------------------
#define KP 136

__global__ __launch_bounds__(512) void k_gather_project(const unsigned* __restrict__ xb,
                                                        const int* __restrict__ offsets,
                                                        const int2* __restrict__ pe,
                                                        const float* __restrict__ W,
                                                        float* __restrict__ out) {
    __shared__ __align__(16) unsigned short Wb[D][KP];    // [f][k] bf16, 34816 B
    __shared__ __align__(16) unsigned short As[64][KP];   // [n][k] bf16, 17408 B

    const int tid = threadIdx.x;
    const long nb = (long)blockIdx.x * 64;

    // stage W -> Wb[f][k] bf16 (4096 float4 over 512 threads)
    const float4* W4 = (const float4*)W;
    #pragma unroll
    for (int it = 0; it < 8; ++it) {
        int idx = it * 512 + tid;
        int f = idx >> 5, kq = idx & 31;
        float4 v = W4[idx];
        *(uint2*)&Wb[f][kq * 4] = make_uint2(bfpk(v.x, v.y), bfpk(v.z, v.w));
    }

    const int w = tid >> 6;           // wave 0..7
    const int lane = tid & 63;

    // gather phase: wave w -> nodes w*8 .. w*8+7
    for (int j = 0; j < 8; ++j) {
        int n = w * 8 + j;
        long node = nb + n;
        int beg = 0, end = 0;
        if (node < NN) { beg = offsets[node]; end = offsets[node + 1]; }
        float a0 = 0.f, a1 = 0.f;
        int2 e = (beg < end) ? pe[beg] : make_int2(0, 0);
        for (int i = beg; i < end; ++i) {
            int2 en = (i + 1 < end) ? pe[i + 1] : make_int2(0, 0);   // prefetch
            unsigned v = xb[(size_t)e.x * 64 + lane];
            float wt = __int_as_float(e.y);
            a0 = fmaf(bflo(v), wt, a0);
            a1 = fmaf(bfhi(v), wt, a1);
            e = en;
        }
        *(unsigned*)&As[n][lane * 2] = bfpk(a0, a1);
    }
    __syncthreads();

    // projection: wave pair (w>>1) owns rows r0..r0+15; wave does 4 col-tiles
    const int lr = lane & 15;
    const int lg = lane >> 4;
    const int r0 = (w >> 1) * 16;
    const int ct0 = (w & 1) * 4;

    bf16x8 afrag[4];
    #pragma unroll
    for (int ks = 0; ks < 4; ++ks)
        afrag[ks] = *(const bf16x8*)&As[r0 + lr][ks * 32 + lg * 8];

    #pragma unroll
    for (int c = 0; c < 4; ++c) {
        int ct = ct0 + c;
        f32x4 acc = {0.f, 0.f, 0.f, 0.f};
        #pragma unroll
        for (int ks = 0; ks < 4; ++ks) {
            bf16x8 bfrag = *(const bf16x8*)&Wb[ct * 16 + lr][ks * 32 + lg * 8];
            acc = __builtin_amdgcn_mfma_f32_16x16x32_bf16(afrag[ks], bfrag, acc, 0, 0, 0);
        }
        #pragma unroll
        for (int r = 0; r < 4; ++r) {
            long gn = nb + r0 + lg * 4 + r;
            if (gn < NN) out[gn * D + ct * 16 + lr] = acc[r];
        }
    }
}

// ---------------------------------------------------------------------------
// tier-2: fp32 gather into out (round-5 verified structure, pe-packed)
// ---------------------------------------------------------------------------
__global__ __launch_bounds__(256) void k_gather_f32(const float* __restrict__ x,
                                                    const int* __restrict__ offsets,
                                                    const int2* __restrict__ pe,
                                                    float* __restrict__ out) {
    int wid = blockIdx.x * 4 + (threadIdx.x >> 6);
    int lane = threadIdx.x & 63;
    if (wid >= NN) return;
    int beg = offsets[wid], end = offsets[wid + 1];
    const float2* x2 = (const float2*)x;
    float a0 = 0.f, a1 = 0.f;
    int2 e = (beg < end) ? pe[beg] : make_int2(0, 0);
    for (int i = beg; i < end; ++i) {
        int2 en = (i + 1 < end) ? pe[i + 1] : make_int2(0, 0);
        float2 v = x2[(size_t)e.x * 64 + lane];
        float w = __int_as_float(e.y);
        a0 = fmaf(v.x, w, a0);
        a1 = fmaf(v.y, w, a1);
        e = en;
    }
    ((float2*)out)[(size_t)wid * 64 + lane] = make_float2(a0, a1);
}

// ---------------------------------------------------------------------------
// standalone MFMA in-place projection (round-9 verified; tiers 2/3)
// ---------------------------------------------------------------------------
__global__ __launch_bounds__(256) void k_project_mfma(const float* __restrict__ W,
                                                      float* __restrict__ io) {
    __shared__ __align__(16) unsigned short Wb[D][KP];
    __shared__ __align__(16) unsigned short As[64][KP];

    const int tid = threadIdx.x;
    const long nb = (long)blockIdx.x * 64;

    const float4* W4 = (const float4*)W;
    #pragma unroll
    for (int it = 0; it < 16; ++it) {
        int idx = it * 256 + tid;
        int f = idx >> 5, kq = idx & 31;
        float4 v = W4[idx];
        *(uint2*)&Wb[f][kq * 4] = make_uint2(bfpk(v.x, v.y), bfpk(v.z, v.w));
    }
    const float4* io4 = (const float4*)io;
    #pragma unroll
    for (int it = 0; it < 8; ++it) {
        int idx = it * 256 + tid;
        int n = idx >> 5, kq = idx & 31;
        long node = nb + n;
        float4 v = (node < NN) ? io4[node * 32 + kq]
                               : make_float4(0.f, 0.f, 0.f, 0.f);
        *(uint2*)&As[n][kq * 4] = make_uint2(bfpk(v.x, v.y), bfpk(v.z, v.w));
    }
    __syncthreads();

    const int w  = tid >> 6;
    const int l  = tid & 63;
    const int lr = l & 15;
    const int lg = l >> 4;
    const int r0 = w * 16;

    bf16x8 afrag[4];
    #pragma unroll
    for (int ks = 0; ks < 4; ++ks)
        afrag[ks] = *(const bf16x8*)&As[r0 + lr][ks * 32 + lg * 8];

    #pragma unroll
    for (int ct = 0; ct < 8; ++ct) {
        f32x4 acc = {0.f, 0.f, 0.f, 0.f};
        #pragma unroll
        for (int ks = 0; ks < 4; ++ks) {
            bf16x8 bfrag = *(const bf16x8*)&Wb[ct * 16 + lr][ks * 32 + lg * 8];
            acc = __builtin_amdgcn_mfma_f32_16x16x32_bf16(afrag[ks], bfrag, acc, 0, 0, 0);
        }
        #pragma unroll
        for (int r = 0; r < 4; ++r) {
            long gn = nb + r0 + lg * 4 + r;
            if (gn < NN) io[gn * D + ct * 16 + lr] = acc[r];
        }
    }
}

// ---------------------------------------------------------------------------
// tier-3 fallback: direct atomic scatter in x-space
// ---------------------------------------------------------------------------
__global__ __launch_bounds__(256) void gcn_scatter(const float* __restrict__ x,
                                                   const float* __restrict__ ew,
                                                   const int* __restrict__ src,
                                                   const int* __restrict__ tgt,
                                                   float* __restrict__ out) {
    int tid = blockIdx.x * 256 + threadIdx.x;
    int e = tid >> 5;
    int t = tid & 31;
    if (e >= NE) return;
    int s = src[e];
    int g = tgt[e];
    float w = ew[e];
    float4 xv = reinterpret_cast<const float4*>(x)[s * 32 + t];
    float* dst = out + (size_t)g * D + (t << 2);
    atomicAdd(dst + 0, xv.x * w);
    atomicAdd(dst + 1, xv.y * w);
    atomicAdd(dst + 2, xv.z * w);
    atomicAdd(dst + 3, xv.w * w);
}

extern "C" void kernel_launch(void* const* d_in, const int* in_sizes, int n_in,
                              void* d_out, int out_size, void* d_ws, size_t ws_size,
                              hipStream_t stream) {
    const float* x   = (const float*)d_in[0];
    const float* W   = (const float*)d_in[1];
    const float* ew  = (const float*)d_in[2];
    const int*   src = (const int*)d_in[3];
    const int*   tgt = (const int*)d_in[4];
    float* out = (float*)d_out;

    if (ws_size >= WS_T2) {
        char* ws = (char*)d_ws;
        int*  counts  = (int*)(ws + OFF_COUNTS);
        int*  offsets = (int*)(ws + OFF_OFFSETS);
        int*  cursor  = (int*)(ws + OFF_CURSOR);
        int*  bsum    = (int*)(ws + OFF_BSUM);
        int*  bsumex  = (int*)(ws + OFF_BSUMEX);
        int2* pe      = (int2*)(ws + OFF_PE);

        hipMemsetAsync(counts, 0, (size_t)NN * sizeof(int), stream);
        k_hist<<<(NE + 255) / 256, 256, 0, stream>>>(tgt, counts);
        k_scan_part<<<NBLK, 256, 0, stream>>>(counts, bsum);
        k_scan_mid<<<1, 128, 0, stream>>>(bsum, bsumex, offsets);
        k_scan_final<<<NBLK, 256, 0, stream>>>(counts, bsumex, offsets, cursor);

        if (ws_size >= WS_FULL) {
            unsigned* xb = (unsigned*)(ws + OFF_XB);
            k_fill_conv<<<FILL_BLKS + CONV_BLKS, 256, 0, stream>>>(src, tgt, ew, cursor, pe, x, xb);
            k_gather_project<<<(NN + 63) / 64, 512, 0, stream>>>(xb, offsets, pe, W, out);
        } else {
            k_fill<<<FILL_BLKS, 256, 0, stream>>>(src, tgt, ew, cursor, pe);
            k_gather_f32<<<(NN + 3) / 4, 256, 0, stream>>>(x, offsets, pe, out);
            k_project_mfma<<<(NN + 63) / 64, 256, 0, stream>>>(W, out);
        }
    } else {
        hipMemsetAsync(out, 0, (size_t)out_size * sizeof(float), stream);
        gcn_scatter<<<(NE * 32 + 255) / 256, 256, 0, stream>>>(x, ew, src, tgt, out);
        k_project_mfma<<<(NN + 63) / 64, 256, 0, stream>>>(W, out);
    }
}

// Round 12
// 255.620 us; speedup vs baseline: 1.0358x; 1.0358x over previous
//
#include <hip/hip_runtime.h>
#include <hip/hip_bf16.h>

#define NN 100000
#define NE 640000
#define D 128

#define SCAN_CHUNK 1024
#define NBLK ((NN + SCAN_CHUNK - 1) / SCAN_CHUNK)   // 98

// ---- workspace layout (bytes) ----
#define OFF_COUNTS  0u                         // NN*4 (dead after scan_final; Wbf reuses it)
#define OFF_WBF     0u                         // 32768 B bf16 W[f][k], written by fill_conv
#define OFF_OFFSETS 400000u                    // (NN+1)*4, padded
#define OFF_CURSOR  800016u                    // NN*4
#define OFF_BSUM    1200016u                   // 512 B
#define OFF_BSUMEX  1200528u                   // 512 B (unused, kept for layout stability)
#define OFF_PE      1201040u                   // NE*8  (int2 packed src,w)
#define WS_T2       6321040u                   // tier-2 end
#define OFF_XB      6321040u                   // NN*64*4 (packed bf16x2 rows)
#define WS_FULL     31921040u                  // tier-1 end

typedef __attribute__((ext_vector_type(8))) short bf16x8;
typedef __attribute__((ext_vector_type(4))) float f32x4;

__device__ __forceinline__ float bflo(unsigned u) { return __uint_as_float(u << 16); }
__device__ __forceinline__ float bfhi(unsigned u) { return __uint_as_float(u & 0xffff0000u); }
__device__ __forceinline__ unsigned bfpk(float x, float y) {
    __hip_bfloat16 bx = __float2bfloat16(x), by = __float2bfloat16(y);
    return (unsigned)(*(unsigned short*)&bx) | ((unsigned)(*(unsigned short*)&by) << 16);
}

// ---------------------------------------------------------------------------
// histogram of targets
// ---------------------------------------------------------------------------
__global__ __launch_bounds__(256) void k_hist(const int* __restrict__ tgt,
                                              int* __restrict__ counts) {
    int e = blockIdx.x * 256 + threadIdx.x;
    if (e < NE) atomicAdd(&counts[tgt[e]], 1);
}

// ---------------------------------------------------------------------------
// scan, 2 kernels: per-block partial sums, then final (each block reduces the
// 98 block-sums itself -- merges the old mid kernel, one fewer dispatch)
// ---------------------------------------------------------------------------
__global__ __launch_bounds__(256) void k_scan_part(const int* __restrict__ counts,
                                                   int* __restrict__ bsum) {
    __shared__ int sd[256];
    int b = blockIdx.x, t = threadIdx.x;
    int base = b * SCAN_CHUNK + t * 4;
    int s = 0;
    #pragma unroll
    for (int k = 0; k < 4; ++k) { int i = base + k; s += (i < NN) ? counts[i] : 0; }
    sd[t] = s; __syncthreads();
    for (int off = 128; off > 0; off >>= 1) {
        if (t < off) sd[t] += sd[t + off];
        __syncthreads();
    }
    if (t == 0) bsum[b] = sd[0];
}

__global__ __launch_bounds__(256) void k_scan_final(const int* __restrict__ counts,
                                                    const int* __restrict__ bsum,
                                                    int* __restrict__ offsets,
                                                    int* __restrict__ cursor) {
    __shared__ int sd[256];
    int b = blockIdx.x, t = threadIdx.x;

    // block base = sum of bsum[0..b-1]  (b <= 97 < 256)
    sd[t] = (t < b) ? bsum[t] : 0;
    __syncthreads();
    for (int off = 128; off > 0; off >>= 1) {
        if (t < off) sd[t] += sd[t + off];
        __syncthreads();
    }
    int base_b = sd[0];
    __syncthreads();

    int base = b * SCAN_CHUNK + t * 4;
    int c[4]; int s = 0;
    #pragma unroll
    for (int k = 0; k < 4; ++k) { int i = base + k; c[k] = (i < NN) ? counts[i] : 0; s += c[k]; }
    sd[t] = s; __syncthreads();
    for (int off = 1; off < 256; off <<= 1) {
        int tmp = (t >= off) ? sd[t - off] : 0;
        __syncthreads();
        sd[t] += tmp;
        __syncthreads();
    }
    int run = sd[t] - s + base_b;
    #pragma unroll
    for (int k = 0; k < 4; ++k) {
        int i = base + k;
        if (i < NN) { offsets[i] = run; cursor[i] = run; }
        run += c[k];
    }
    if (b == 0 && t == 0) offsets[NN] = NE;
}

// ---------------------------------------------------------------------------
// fused: bucket edges | x->bf16 conv | W->bf16 [f][k] conv (block-range split)
// Wbf reuses the counts region (dead after scan_final).
// ---------------------------------------------------------------------------
#define FILL_BLKS ((NE + 255) / 256)           // 2500
#define CONV_BLKS ((NN * 64 + 255) / 256)      // 25000
#define WBF_BLKS  16                           // 4096 float4 of W

__global__ __launch_bounds__(256) void k_fill_conv(const int* __restrict__ src,
                                                   const int* __restrict__ tgt,
                                                   const float* __restrict__ ew,
                                                   int* __restrict__ cursor,
                                                   int2* __restrict__ pe,
                                                   const float* __restrict__ x,
                                                   unsigned* __restrict__ xb,
                                                   const float* __restrict__ W,
                                                   unsigned* __restrict__ wbf) {
    int b = blockIdx.x;
    if (b < FILL_BLKS) {
        int e = b * 256 + threadIdx.x;
        if (e < NE) {
            int t = tgt[e];
            int p = atomicAdd(&cursor[t], 1);
            pe[p] = make_int2(src[e], __float_as_int(ew[e]));
        }
    } else if (b < FILL_BLKS + CONV_BLKS) {
        int i = (b - FILL_BLKS) * 256 + threadIdx.x;
        if (i < NN * 64) {
            float2 v = ((const float2*)x)[i];
            xb[i] = bfpk(v.x, v.y);
        }
    } else {
        int idx = (b - FILL_BLKS - CONV_BLKS) * 256 + threadIdx.x;  // 0..4095
        int f = idx >> 5, kq = idx & 31;
        float4 v = ((const float4*)W)[idx];
        *(uint2*)&wbf[f * 64 + kq * 2] = make_uint2(bfpk(v.x, v.y), bfpk(v.z, v.w));
    }
}

// tier-2 variant: fill only
__global__ __launch_bounds__(256) void k_fill(const int* __restrict__ src,
                                              const int* __restrict__ tgt,
                                              const float* __restrict__ ew,
                                              int* __restrict__ cursor,
                                              int2* __restrict__ pe) {
    int e = blockIdx.x * 256 + threadIdx.x;
    if (e < NE) {
        int t = tgt[e];
        int p = atomicAdd(&cursor[t], 1);
        pe[p] = make_int2(src[e], __float_as_int(ew[e]));
    }
}

// ---------------------------------------------------------------------------
// FUSED gather + MFMA projection (tier-1), As-only LDS (17.4 KB).
// 512 thr = 8 waves, 64 nodes/block. Wave w gathers nodes w*8..w*8+7 into
// LDS As (bf16), barrier, then wave-pairs project 16 rows x 4 col-tiles via
// mfma_f32_16x16x32_bf16 with B-frags loaded from global bf16 W (L1/L2-hot).
// LDS 17.4 KB + 512 thr -> 4 blocks/CU = 32 waves/CU (wave-slot bound).
// ---------------------------------------------------------------------------
#define KP 136

__global__ __launch_bounds__(512) void k_gather_project(const unsigned* __restrict__ xb,
                                                        const int* __restrict__ offsets,
                                                        const int2* __restrict__ pe,
                                                        const unsigned short* __restrict__ wbf,
                                                        float* __restrict__ out) {
    __shared__ __align__(16) unsigned short As[64][KP];   // [n][k] bf16, 17408 B

    const int tid = threadIdx.x;
    const long nb = (long)blockIdx.x * 64;

    const int w = tid >> 6;           // wave 0..7
    const int lane = tid & 63;

    // gather phase: wave w -> nodes w*8 .. w*8+7
    for (int j = 0; j < 8; ++j) {
        int n = w * 8 + j;
        long node = nb + n;
        int beg = 0, end = 0;
        if (node < NN) { beg = offsets[node]; end = offsets[node + 1]; }
        float a0 = 0.f, a1 = 0.f;
        int2 e = (beg < end) ? pe[beg] : make_int2(0, 0);
        for (int i = beg; i < end; ++i) {
            int2 en = (i + 1 < end) ? pe[i + 1] : make_int2(0, 0);   // prefetch
            unsigned v = xb[(size_t)e.x * 64 + lane];
            float wt = __int_as_float(e.y);
            a0 = fmaf(bflo(v), wt, a0);
            a1 = fmaf(bfhi(v), wt, a1);
            e = en;
        }
        *(unsigned*)&As[n][lane * 2] = bfpk(a0, a1);
    }
    __syncthreads();

    // projection: wave pair (w>>1) owns rows r0..r0+15; wave does 4 col-tiles
    const int lr = lane & 15;
    const int lg = lane >> 4;
    const int r0 = (w >> 1) * 16;
    const int ct0 = (w & 1) * 4;

    bf16x8 afrag[4];
    #pragma unroll
    for (int ks = 0; ks < 4; ++ks)
        afrag[ks] = *(const bf16x8*)&As[r0 + lr][ks * 32 + lg * 8];

    #pragma unroll
    for (int c = 0; c < 4; ++c) {
        int ct = ct0 + c;
        f32x4 acc = {0.f, 0.f, 0.f, 0.f};
        #pragma unroll
        for (int ks = 0; ks < 4; ++ks) {
            bf16x8 bfrag = *(const bf16x8*)&wbf[(ct * 16 + lr) * 128 + ks * 32 + lg * 8];
            acc = __builtin_amdgcn_mfma_f32_16x16x32_bf16(afrag[ks], bfrag, acc, 0, 0, 0);
        }
        #pragma unroll
        for (int r = 0; r < 4; ++r) {
            long gn = nb + r0 + lg * 4 + r;
            if (gn < NN) out[gn * D + ct * 16 + lr] = acc[r];
        }
    }
}

// ---------------------------------------------------------------------------
// tier-2: fp32 gather into out (round-5 verified structure, pe-packed)
// ---------------------------------------------------------------------------
__global__ __launch_bounds__(256) void k_gather_f32(const float* __restrict__ x,
                                                    const int* __restrict__ offsets,
                                                    const int2* __restrict__ pe,
                                                    float* __restrict__ out) {
    int wid = blockIdx.x * 4 + (threadIdx.x >> 6);
    int lane = threadIdx.x & 63;
    if (wid >= NN) return;
    int beg = offsets[wid], end = offsets[wid + 1];
    const float2* x2 = (const float2*)x;
    float a0 = 0.f, a1 = 0.f;
    int2 e = (beg < end) ? pe[beg] : make_int2(0, 0);
    for (int i = beg; i < end; ++i) {
        int2 en = (i + 1 < end) ? pe[i + 1] : make_int2(0, 0);
        float2 v = x2[(size_t)e.x * 64 + lane];
        float w = __int_as_float(e.y);
        a0 = fmaf(v.x, w, a0);
        a1 = fmaf(v.y, w, a1);
        e = en;
    }
    ((float2*)out)[(size_t)wid * 64 + lane] = make_float2(a0, a1);
}

// ---------------------------------------------------------------------------
// standalone MFMA in-place projection (round-9 verified; tiers 2/3)
// ---------------------------------------------------------------------------
__global__ __launch_bounds__(256) void k_project_mfma(const float* __restrict__ W,
                                                      float* __restrict__ io) {
    __shared__ __align__(16) unsigned short Wb[D][KP];
    __shared__ __align__(16) unsigned short As[64][KP];

    const int tid = threadIdx.x;
    const long nb = (long)blockIdx.x * 64;

    const float4* W4 = (const float4*)W;
    #pragma unroll
    for (int it = 0; it < 16; ++it) {
        int idx = it * 256 + tid;
        int f = idx >> 5, kq = idx & 31;
        float4 v = W4[idx];
        *(uint2*)&Wb[f][kq * 4] = make_uint2(bfpk(v.x, v.y), bfpk(v.z, v.w));
    }
    const float4* io4 = (const float4*)io;
    #pragma unroll
    for (int it = 0; it < 8; ++it) {
        int idx = it * 256 + tid;
        int n = idx >> 5, kq = idx & 31;
        long node = nb + n;
        float4 v = (node < NN) ? io4[node * 32 + kq]
                               : make_float4(0.f, 0.f, 0.f, 0.f);
        *(uint2*)&As[n][kq * 4] = make_uint2(bfpk(v.x, v.y), bfpk(v.z, v.w));
    }
    __syncthreads();

    const int w  = tid >> 6;
    const int l  = tid & 63;
    const int lr = l & 15;
    const int lg = l >> 4;
    const int r0 = w * 16;

    bf16x8 afrag[4];
    #pragma unroll
    for (int ks = 0; ks < 4; ++ks)
        afrag[ks] = *(const bf16x8*)&As[r0 + lr][ks * 32 + lg * 8];

    #pragma unroll
    for (int ct = 0; ct < 8; ++ct) {
        f32x4 acc = {0.f, 0.f, 0.f, 0.f};
        #pragma unroll
        for (int ks = 0; ks < 4; ++ks) {
            bf16x8 bfrag = *(const bf16x8*)&Wb[ct * 16 + lr][ks * 32 + lg * 8];
            acc = __builtin_amdgcn_mfma_f32_16x16x32_bf16(afrag[ks], bfrag, acc, 0, 0, 0);
        }
        #pragma unroll
        for (int r = 0; r < 4; ++r) {
            long gn = nb + r0 + lg * 4 + r;
            if (gn < NN) io[gn * D + ct * 16 + lr] = acc[r];
        }
    }
}

// ---------------------------------------------------------------------------
// tier-3 fallback: direct atomic scatter in x-space
// ---------------------------------------------------------------------------
__global__ __launch_bounds__(256) void gcn_scatter(const float* __restrict__ x,
                                                   const float* __restrict__ ew,
                                                   const int* __restrict__ src,
                                                   const int* __restrict__ tgt,
                                                   float* __restrict__ out) {
    int tid = blockIdx.x * 256 + threadIdx.x;
    int e = tid >> 5;
    int t = tid & 31;
    if (e >= NE) return;
    int s = src[e];
    int g = tgt[e];
    float w = ew[e];
    float4 xv = reinterpret_cast<const float4*>(x)[s * 32 + t];
    float* dst = out + (size_t)g * D + (t << 2);
    atomicAdd(dst + 0, xv.x * w);
    atomicAdd(dst + 1, xv.y * w);
    atomicAdd(dst + 2, xv.z * w);
    atomicAdd(dst + 3, xv.w * w);
}

extern "C" void kernel_launch(void* const* d_in, const int* in_sizes, int n_in,
                              void* d_out, int out_size, void* d_ws, size_t ws_size,
                              hipStream_t stream) {
    const float* x   = (const float*)d_in[0];
    const float* W   = (const float*)d_in[1];
    const float* ew  = (const float*)d_in[2];
    const int*   src = (const int*)d_in[3];
    const int*   tgt = (const int*)d_in[4];
    float* out = (float*)d_out;

    if (ws_size >= WS_T2) {
        char* ws = (char*)d_ws;
        int*  counts  = (int*)(ws + OFF_COUNTS);
        int*  offsets = (int*)(ws + OFF_OFFSETS);
        int*  cursor  = (int*)(ws + OFF_CURSOR);
        int*  bsum    = (int*)(ws + OFF_BSUM);
        int2* pe      = (int2*)(ws + OFF_PE);

        hipMemsetAsync(counts, 0, (size_t)NN * sizeof(int), stream);
        k_hist<<<(NE + 255) / 256, 256, 0, stream>>>(tgt, counts);
        k_scan_part<<<NBLK, 256, 0, stream>>>(counts, bsum);
        k_scan_final<<<NBLK, 256, 0, stream>>>(counts, bsum, offsets, cursor);

        if (ws_size >= WS_FULL) {
            unsigned* xb  = (unsigned*)(ws + OFF_XB);
            unsigned* wbf = (unsigned*)(ws + OFF_WBF);    // reuses dead counts region
            k_fill_conv<<<FILL_BLKS + CONV_BLKS + WBF_BLKS, 256, 0, stream>>>(
                src, tgt, ew, cursor, pe, x, xb, W, wbf);
            k_gather_project<<<(NN + 63) / 64, 512, 0, stream>>>(
                xb, offsets, pe, (const unsigned short*)wbf, out);
        } else {
            k_fill<<<FILL_BLKS, 256, 0, stream>>>(src, tgt, ew, cursor, pe);
            k_gather_f32<<<(NN + 3) / 4, 256, 0, stream>>>(x, offsets, pe, out);
            k_project_mfma<<<(NN + 63) / 64, 256, 0, stream>>>(W, out);
        }
    } else {
        hipMemsetAsync(out, 0, (size_t)out_size * sizeof(float), stream);
        gcn_scatter<<<(NE * 32 + 255) / 256, 256, 0, stream>>>(x, ew, src, tgt, out);
        k_project_mfma<<<(NN + 63) / 64, 256, 0, stream>>>(W, out);
    }
}